// Round 7
// baseline (331.801 us; speedup 1.0000x reference)
//
#include <hip/hip_runtime.h>
#include <hip/hip_bf16.h>

typedef __bf16 bf16;
typedef __bf16 bf16x8 __attribute__((ext_vector_type(8)));
typedef float f32x4 __attribute__((ext_vector_type(4)));

#define EMB 1024
#define SEQ 2048
#define NH 16
#define HD 64
#define MTOK 8192  // 4*2048

// ---------------- cast kernels ----------------
__global__ __launch_bounds__(256) void cast_f32_bf16(const float* __restrict__ in,
                                                     bf16* __restrict__ out, int n8) {
    int i = blockIdx.x * blockDim.x + threadIdx.x;
    if (i < n8) {
        const float4* p = (const float4*)in + 2 * (size_t)i;
        float4 a = p[0], b = p[1];
        bf16x8 v;
        v[0] = (bf16)a.x; v[1] = (bf16)a.y; v[2] = (bf16)a.z; v[3] = (bf16)a.w;
        v[4] = (bf16)b.x; v[5] = (bf16)b.y; v[6] = (bf16)b.z; v[7] = (bf16)b.w;
        *(bf16x8*)(out + 8 * (size_t)i) = v;
    }
}

// W[K][N] fp32 -> Wt[N][K] bf16
__global__ __launch_bounds__(256) void transpose_cast(const float* __restrict__ W,
                                                      bf16* __restrict__ Wt, int K, int N) {
    __shared__ float tile[32][33];
    int n0 = blockIdx.x * 32, k0 = blockIdx.y * 32;
    int tx = threadIdx.x & 31, ty = threadIdx.x >> 5;  // ty 0..7
    #pragma unroll
    for (int i = 0; i < 32; i += 8)
        tile[ty + i][tx] = W[(size_t)(k0 + ty + i) * N + n0 + tx];
    __syncthreads();
    #pragma unroll
    for (int i = 0; i < 32; i += 8)
        Wt[(size_t)(n0 + ty + i) * K + k0 + tx] = (bf16)tile[tx][ty + i];
}

// ---------------- GEMM 1: x @ W_qkv + b -> Q(scaled) [BH][S][D], K [BH][S][D], V^T [BH][D][S] ----------------
#define BM 128
#define BN 128
#define BK 64
#define LDK 72  // BK + 8 pad

// fold 1/sqrt(64) * log2(e) into Q so attention uses exp2 directly
#define QSCALE 0.1803368801111f

__global__ __launch_bounds__(256) void gemm_qkv(const bf16* __restrict__ A,   // [8192][1024]
                                                const bf16* __restrict__ Bt,  // [3072][1024]
                                                const float* __restrict__ bias,
                                                bf16* __restrict__ qws, bf16* __restrict__ kws,
                                                bf16* __restrict__ vt) {
    __shared__ bf16 sA[BM][LDK];
    __shared__ bf16 sB[BN][LDK];
    const int K = 1024;
    int m0 = blockIdx.x * BM, n0 = blockIdx.y * BN;
    int t = threadIdx.x, lane = t & 63, w = t >> 6;
    int wr = w >> 1, wc = w & 1;
    int l15 = lane & 15, quad = lane >> 4;

    f32x4 acc[4][4];
    #pragma unroll
    for (int i = 0; i < 4; i++)
        #pragma unroll
        for (int j = 0; j < 4; j++) acc[i][j] = (f32x4){0.f, 0.f, 0.f, 0.f};

    int srow = t >> 3, sc8 = (t & 7) * 8;
    for (int kt = 0; kt < K; kt += BK) {
        #pragma unroll
        for (int p = 0; p < 4; p++) {
            int r = srow + p * 32;
            *(uint4*)&sA[r][sc8] = *(const uint4*)(A + (size_t)(m0 + r) * K + kt + sc8);
            *(uint4*)&sB[r][sc8] = *(const uint4*)(Bt + (size_t)(n0 + r) * K + kt + sc8);
        }
        __syncthreads();
        #pragma unroll
        for (int ks = 0; ks < BK; ks += 32) {
            int kk = ks + quad * 8;
            bf16x8 af[4], bfr[4];
            #pragma unroll
            for (int mt = 0; mt < 4; mt++) af[mt] = *(const bf16x8*)&sA[wr * 64 + mt * 16 + l15][kk];
            #pragma unroll
            for (int nt = 0; nt < 4; nt++) bfr[nt] = *(const bf16x8*)&sB[wc * 64 + nt * 16 + l15][kk];
            #pragma unroll
            for (int mt = 0; mt < 4; mt++)
                #pragma unroll
                for (int nt = 0; nt < 4; nt++)
                    acc[mt][nt] = __builtin_amdgcn_mfma_f32_16x16x32_bf16(af[mt], bfr[nt], acc[mt][nt], 0, 0, 0);
        }
        __syncthreads();
    }
    // epilogue: route to Q (scaled) / K / V^T
    #pragma unroll
    for (int mt = 0; mt < 4; mt++)
        #pragma unroll
        for (int nt = 0; nt < 4; nt++) {
            int col = n0 + wc * 64 + nt * 16 + l15;
            float bv = bias[col];
            int mat = col >> 10;  // wave-uniform per block (1024 % 128 == 0)
            int e = col & 1023;
            int h = e >> 6, d = e & 63;
            int row0 = m0 + wr * 64 + mt * 16 + quad * 4;
            int bb = row0 >> 11, s0 = row0 & 2047;
            int bh = bb * NH + h;
            float vv[4];
            #pragma unroll
            for (int r = 0; r < 4; r++) vv[r] = acc[mt][nt][r] + bv;
            if (mat == 0) {
                #pragma unroll
                for (int r = 0; r < 4; r++)
                    qws[((size_t)bh * SEQ + s0 + r) * HD + d] = (bf16)(vv[r] * QSCALE);
            } else if (mat == 1) {
                #pragma unroll
                for (int r = 0; r < 4; r++)
                    kws[((size_t)bh * SEQ + s0 + r) * HD + d] = (bf16)vv[r];
            } else {
                // V^T: vt[bh][d][s]; lane holds 4 consecutive s at fixed d -> one 8B store
                ushort4 pk;
                pk.x = __builtin_bit_cast(unsigned short, (bf16)vv[0]);
                pk.y = __builtin_bit_cast(unsigned short, (bf16)vv[1]);
                pk.z = __builtin_bit_cast(unsigned short, (bf16)vv[2]);
                pk.w = __builtin_bit_cast(unsigned short, (bf16)vv[3]);
                *(ushort4*)((unsigned short*)vt + ((size_t)bh * HD + d) * SEQ + s0) = pk;
            }
        }
}

// ---------------- Flash attention: barrier-free, direct-global K/V frags, 64 q/wave ----------------
// Grid: 1D 512 blocks; bh = id & 63 so all 8 q-blocks of a bh land on one XCD (id%8 = bh%8)
// and both blocks of a CU share the K/V stream (L1/L2-resident; no LDS staging, no barriers).
// S^T = K*Q^T; P round-trips through wave-private LDS slab (pitch 72 -> b128 reads).
#define PQP 72
__global__ __launch_bounds__(256, 2) void attn(const bf16* __restrict__ qws, const bf16* __restrict__ kws,
                                               const bf16* __restrict__ vt, bf16* __restrict__ ao) {
    __shared__ bf16 sPq[256][PQP];  // P [q][kv], wave-private 64-row slabs, granule-rotated

    int id = blockIdx.x;
    int qx = id >> 6, bh = id & 63;
    int q0 = qx * 256;
    int t = threadIdx.x, lane = t & 63, w = t >> 6;
    int l15 = lane & 15, quad = lane >> 4;
    int ql = quad & 1, qh = quad >> 1;

    const bf16* qb = qws + (size_t)bh * SEQ * HD;
    const bf16* kb = kws + (size_t)bh * SEQ * HD;
    const bf16* vtb = vt + (size_t)bh * HD * SEQ;

    // Q B-frags: lane holds Q[q=l15][d=quad*8+j]; 4 nq x 2 ks
    bf16x8 qf[4][2];
    #pragma unroll
    for (int nq = 0; nq < 4; nq++)
        #pragma unroll
        for (int ks = 0; ks < 2; ks++)
            qf[nq][ks] = *(const bf16x8*)(qb + (size_t)(q0 + w * 64 + nq * 16 + l15) * HD + ks * 32 + quad * 8);

    f32x4 o[4][4];  // O^T [d-tile mt][q-tile nq]
    float lsum[4] = {0.f, 0.f, 0.f, 0.f};
    #pragma unroll
    for (int mt = 0; mt < 4; mt++)
        #pragma unroll
        for (int nq = 0; nq < 4; nq++) o[mt][nq] = (f32x4){0.f, 0.f, 0.f, 0.f};

    unsigned int* myP = (unsigned int*)&sPq[w * 64][0];  // wave slab; row stride 36 dwords

    for (int kv0 = 0; kv0 < SEQ; kv0 += 64) {
        // ---- S^T = K*Q^T, fused exp2 + packed P write, 16 kv rows at a time ----
        bf16x8 kf[4][2];
        #pragma unroll
        for (int nt = 0; nt < 4; nt++)
            #pragma unroll
            for (int ks = 0; ks < 2; ks++)
                kf[nt][ks] = *(const bf16x8*)(kb + (size_t)(kv0 + nt * 16 + l15) * HD + ks * 32 + quad * 8);

        #pragma unroll
        for (int nt = 0; nt < 4; nt++) {
            f32x4 sacc[4];
            #pragma unroll
            for (int nq = 0; nq < 4; nq++) sacc[nq] = (f32x4){0.f, 0.f, 0.f, 0.f};
            #pragma unroll
            for (int ks = 0; ks < 2; ks++)
                #pragma unroll
                for (int nq = 0; nq < 4; nq++)
                    sacc[nq] = __builtin_amdgcn_mfma_f32_16x16x32_bf16(kf[nt][ks], qf[nq][ks], sacc[nq], 0, 0, 0);
            int g = 2 * nt + qh;
            int cdw = (((g + l15) & 7) << 2) | (ql << 1);  // granule rotate by row, 8B slot
            #pragma unroll
            for (int nq = 0; nq < 4; nq++) {
                float p0 = __builtin_amdgcn_exp2f(sacc[nq][0]);
                float p1 = __builtin_amdgcn_exp2f(sacc[nq][1]);
                float p2 = __builtin_amdgcn_exp2f(sacc[nq][2]);
                float p3 = __builtin_amdgcn_exp2f(sacc[nq][3]);
                lsum[nq] += (p0 + p1) + (p2 + p3);
                unsigned int u0 = (unsigned int)__builtin_bit_cast(unsigned short, (bf16)p0) |
                                  ((unsigned int)__builtin_bit_cast(unsigned short, (bf16)p1) << 16);
                unsigned int u1 = (unsigned int)__builtin_bit_cast(unsigned short, (bf16)p2) |
                                  ((unsigned int)__builtin_bit_cast(unsigned short, (bf16)p3) << 16);
                *(uint2*)(myP + (nq * 16 + l15) * (PQP / 2) + cdw) = make_uint2(u0, u1);
            }
        }
        __threadfence_block();  // wave-private slab: order LDS write -> read

        // ---- O^T += V^T * P^T : A-frags direct from global V^T, B-frags b128 from own slab ----
        #pragma unroll
        for (int ks2 = 0; ks2 < 2; ks2++) {
            bf16x8 pb[4];
            int gr = ((ks2 * 4 + quad + l15) & 7) << 2;
            #pragma unroll
            for (int nq = 0; nq < 4; nq++)
                pb[nq] = *(const bf16x8*)(myP + (nq * 16 + l15) * (PQP / 2) + gr);
            #pragma unroll
            for (int mt = 0; mt < 4; mt++) {
                bf16x8 vf = *(const bf16x8*)(vtb + (size_t)(mt * 16 + l15) * SEQ + kv0 + ks2 * 32 + quad * 8);
                #pragma unroll
                for (int nq = 0; nq < 4; nq++)
                    o[mt][nq] = __builtin_amdgcn_mfma_f32_16x16x32_bf16(vf, pb[nq], o[mt][nq], 0, 0, 0);
            }
        }
    }

    // row sums: quads hold disjoint kv partials at fixed q=l15 -> 2 shuffles
    float inv[4];
    #pragma unroll
    for (int nq = 0; nq < 4; nq++) {
        float s = lsum[nq];
        s += __shfl_xor(s, 16);
        s += __shfl_xor(s, 32);
        inv[nq] = __builtin_amdgcn_rcpf(s);
    }

    // epilogue: O^T[d][q] -> ao[b][s=q][h*64+d], 8B stores
    int h = bh & 15, bb = bh >> 4;
    #pragma unroll
    for (int mt = 0; mt < 4; mt++)
        #pragma unroll
        for (int nq = 0; nq < 4; nq++) {
            int srow = q0 + w * 64 + nq * 16 + l15;
            int col = h * HD + mt * 16 + quad * 4;
            ushort4 pk;
            pk.x = __builtin_bit_cast(unsigned short, (bf16)(o[mt][nq][0] * inv[nq]));
            pk.y = __builtin_bit_cast(unsigned short, (bf16)(o[mt][nq][1] * inv[nq]));
            pk.z = __builtin_bit_cast(unsigned short, (bf16)(o[mt][nq][2] * inv[nq]));
            pk.w = __builtin_bit_cast(unsigned short, (bf16)(o[mt][nq][3] * inv[nq]));
            *(ushort4*)((unsigned short*)ao + ((size_t)(bb * SEQ + srow)) * EMB + col) = pk;
        }
}

// ---------------- GEMM 2: ao @ W_out + b_out -> out fp32 ----------------
__global__ __launch_bounds__(256) void gemm_out(const bf16* __restrict__ A,   // [8192][1024]
                                                const bf16* __restrict__ Bt,  // [1024][1024]
                                                const float* __restrict__ bias,
                                                float* __restrict__ out) {
    __shared__ bf16 sA[BM][LDK];
    __shared__ bf16 sB[BN][LDK];
    const int K = 1024;
    int m0 = blockIdx.x * BM, n0 = blockIdx.y * BN;
    int t = threadIdx.x, lane = t & 63, w = t >> 6;
    int wr = w >> 1, wc = w & 1;
    int l15 = lane & 15, quad = lane >> 4;

    f32x4 acc[4][4];
    #pragma unroll
    for (int i = 0; i < 4; i++)
        #pragma unroll
        for (int j = 0; j < 4; j++) acc[i][j] = (f32x4){0.f, 0.f, 0.f, 0.f};

    int srow = t >> 3, sc8 = (t & 7) * 8;
    for (int kt = 0; kt < K; kt += BK) {
        #pragma unroll
        for (int p = 0; p < 4; p++) {
            int r = srow + p * 32;
            *(uint4*)&sA[r][sc8] = *(const uint4*)(A + (size_t)(m0 + r) * K + kt + sc8);
            *(uint4*)&sB[r][sc8] = *(const uint4*)(Bt + (size_t)(n0 + r) * K + kt + sc8);
        }
        __syncthreads();
        #pragma unroll
        for (int ks = 0; ks < BK; ks += 32) {
            int kk = ks + quad * 8;
            bf16x8 af[4], bfr[4];
            #pragma unroll
            for (int mt = 0; mt < 4; mt++) af[mt] = *(const bf16x8*)&sA[wr * 64 + mt * 16 + l15][kk];
            #pragma unroll
            for (int nt = 0; nt < 4; nt++) bfr[nt] = *(const bf16x8*)&sB[wc * 64 + nt * 16 + l15][kk];
            #pragma unroll
            for (int mt = 0; mt < 4; mt++)
                #pragma unroll
                for (int nt = 0; nt < 4; nt++)
                    acc[mt][nt] = __builtin_amdgcn_mfma_f32_16x16x32_bf16(af[mt], bfr[nt], acc[mt][nt], 0, 0, 0);
        }
        __syncthreads();
    }
    #pragma unroll
    for (int mt = 0; mt < 4; mt++)
        #pragma unroll
        for (int nt = 0; nt < 4; nt++) {
            int col = n0 + wc * 64 + nt * 16 + l15;
            float bv = bias[col];
            #pragma unroll
            for (int r = 0; r < 4; r++) {
                int row = m0 + wr * 64 + mt * 16 + quad * 4 + r;
                out[(size_t)row * EMB + col] = acc[mt][nt][r] + bv;
            }
        }
}

// ---------------- launch ----------------
extern "C" void kernel_launch(void* const* d_in, const int* in_sizes, int n_in,
                              void* d_out, int out_size, void* d_ws, size_t ws_size,
                              hipStream_t stream) {
    const float* x     = (const float*)d_in[0];
    const float* W_qkv = (const float*)d_in[1];
    const float* b_qkv = (const float*)d_in[2];
    const float* W_out = (const float*)d_in[3];
    const float* b_out = (const float*)d_in[4];
    float* out = (float*)d_out;

    char* ws = (char*)d_ws;
    bf16* xb    = (bf16*)(ws);
    bf16* wqkvT = (bf16*)(ws + (size_t)(16 << 20));
    bf16* woutT = (bf16*)(ws + (size_t)(22 << 20));
    bf16* qws   = (bf16*)(ws + (size_t)(24 << 20));
    bf16* kws   = (bf16*)(ws + (size_t)(40 << 20));
    bf16* vt    = (bf16*)(ws + (size_t)(56 << 20));
    bf16* aow   = (bf16*)(ws + (size_t)(72 << 20));

    cast_f32_bf16<<<4096, 256, 0, stream>>>(x, xb, MTOK * EMB / 8);
    transpose_cast<<<dim3(3 * EMB / 32, EMB / 32), 256, 0, stream>>>(W_qkv, wqkvT, EMB, 3 * EMB);
    transpose_cast<<<dim3(EMB / 32, EMB / 32), 256, 0, stream>>>(W_out, woutT, EMB, EMB);
    gemm_qkv<<<dim3(MTOK / BM, 3 * EMB / BN), 256, 0, stream>>>(xb, wqkvT, b_qkv, qws, kws, vt);
    attn<<<dim3(512), 256, 0, stream>>>(qws, kws, vt, aow);
    gemm_out<<<dim3(MTOK / BM, EMB / BN), 256, 0, stream>>>(aow, woutT, b_out, out);
}